// Round 16
// baseline (240.944 us; speedup 1.0000x reference)
//
#include <hip/hip_runtime.h>
#include <hip/hip_bf16.h>
#include <stdint.h>

#define DEVI __device__ __forceinline__
typedef unsigned short u16;
typedef unsigned int u32;
typedef unsigned char u8;
typedef __attribute__((ext_vector_type(2))) float f32x2;
typedef __attribute__((ext_vector_type(4))) float f32x4;
typedef __attribute__((ext_vector_type(2))) u32 u32x2;
typedef __attribute__((ext_vector_type(4))) u32 u32x4;
typedef __attribute__((ext_vector_type(8))) __bf16 bf16x8;

#define B_ 2
#define LSEQ 2048
#define HN 16
#define DMODEL 1024
#define MROWS (B_ * LSEQ) /* 4096 */
#define TILE_ELEMS (128 * 64)
#define TILE_BYTES (128 * 64 * 2)

DEVI u16 f2bf(float f) {
  u32 u = __float_as_uint(f);
  return (u16)((u + 0x7fffu + ((u >> 16) & 1u)) >> 16);
}
DEVI float bf2f(u16 h) { return __uint_as_float(((u32)h) << 16); }
DEVI u32 pk2(float a, float b) { return (u32)f2bf(a) | ((u32)f2bf(b) << 16); }

DEVI f32x4 mfma16(bf16x8 a, bf16x8 b, f32x4 c) {
  return __builtin_amdgcn_mfma_f32_16x16x32_bf16(a, b, c, 0, 0, 0);
}
DEVI f32x4 mfma_fp8(u32x2 a, u32x2 b, f32x4 c) {
  return __builtin_amdgcn_mfma_f32_16x16x32_fp8_fp8(
      __builtin_bit_cast(long, a), __builtin_bit_cast(long, b), c, 0, 0, 0);
}
DEVI bf16x8 as_bf(u32x4 v) { return __builtin_bit_cast(bf16x8, v); }

// lgkm-only barrier: does NOT drain vmcnt (outstanding global stores keep
// flowing). Rule #18: sched_barrier fences around the asm waitcnt + barrier.
DEVI void bar_lgkm() {
  __builtin_amdgcn_sched_barrier(0);
  asm volatile("s_waitcnt lgkmcnt(0)" ::: "memory");
  __builtin_amdgcn_sched_barrier(0);
  __builtin_amdgcn_s_barrier();
  __builtin_amdgcn_sched_barrier(0);
}

// async global->LDS 16B: LDS dest = wave-uniform base + lane*16
DEVI void gload16(const void* g, void* l) {
  __builtin_amdgcn_global_load_lds(
      (const __attribute__((address_space(1))) void*)g,
      (__attribute__((address_space(3))) void*)l, 16, 0, 0);
}

// ---------------------------------------------------------------------------
// K0: prep — merged activation + weight prep (proven).
// ---------------------------------------------------------------------------
__global__ __launch_bounds__(256) void prep(const float* __restrict__ q,
                                            const float* __restrict__ k,
                                            const float* __restrict__ v,
                                            const float* __restrict__ wq,
                                            const float* __restrict__ wk,
                                            const float* __restrict__ wv,
                                            const float* __restrict__ wfc,
                                            u16* __restrict__ aps,
                                            u16* __restrict__ wt) {
  const int z = blockIdx.z;
  const int t = threadIdx.x;
  if (z < 3) {
    const float* src = z == 0 ? q : z == 1 ? k : v;
    const int mt = blockIdx.x, kt = blockIdx.y;
    char* db = (char*)(aps + ((size_t)z * 32 * 16 + (size_t)mt * 16 + kt) *
                                 TILE_ELEMS);
#pragma unroll
    for (int i = 0; i < 4; ++i) {
      const int ch = t + i * 256;
      const int r = ch >> 3, c = ch & 7;
      const float* sp = src + (size_t)(mt * 128 + r) * DMODEL + kt * 64 + c * 8;
      f32x4 a = *(const f32x4*)sp;
      f32x4 b = *(const f32x4*)(sp + 4);
      u32x4 o;
      o.x = pk2(a.x, a.y);
      o.y = pk2(a.z, a.w);
      o.z = pk2(b.x, b.y);
      o.w = pk2(b.z, b.w);
      *(u32x4*)(db + r * 128 + ((c ^ (r & 7)) * 16)) = o;
    }
    return;
  }
  if (blockIdx.x >= 16) return;
  __shared__ float tl[64][65];
  const int which = z - 3;
  const float* src = which == 0 ? wq : which == 1 ? wk : which == 2 ? wv : wfc;
  const float scale = which == 0 ? 0.125f : 1.0f;
  const int kt = blockIdx.x;
  const int k0 = kt * 64, n0 = blockIdx.y * 64;
  {
    const int i = t >> 2, jc = (t & 3) * 16;
#pragma unroll
    for (int x = 0; x < 4; ++x) {
      f32x4 f = *(const f32x4*)(src + (size_t)(k0 + i) * DMODEL + n0 + jc + 4 * x);
      tl[i][jc + 4 * x + 0] = f.x;
      tl[i][jc + 4 * x + 1] = f.y;
      tl[i][jc + 4 * x + 2] = f.z;
      tl[i][jc + 4 * x + 3] = f.w;
    }
  }
  __syncthreads();
  {
    const int j = t >> 2, ic = (t & 3) * 16;
    u32x4 o0, o1;
    o0.x = pk2(tl[ic + 0][j] * scale, tl[ic + 1][j] * scale);
    o0.y = pk2(tl[ic + 2][j] * scale, tl[ic + 3][j] * scale);
    o0.z = pk2(tl[ic + 4][j] * scale, tl[ic + 5][j] * scale);
    o0.w = pk2(tl[ic + 6][j] * scale, tl[ic + 7][j] * scale);
    o1.x = pk2(tl[ic + 8][j] * scale, tl[ic + 9][j] * scale);
    o1.y = pk2(tl[ic + 10][j] * scale, tl[ic + 11][j] * scale);
    o1.z = pk2(tl[ic + 12][j] * scale, tl[ic + 13][j] * scale);
    o1.w = pk2(tl[ic + 14][j] * scale, tl[ic + 15][j] * scale);
    const int ntile = blockIdx.y >> 1;
    const int r = ((blockIdx.y & 1) << 6) + j;
    const int c0 = (t & 3) * 2;
    char* db = (char*)(wt + ((size_t)which * 128 + (size_t)ntile * 16 + kt) *
                                TILE_ELEMS);
    *(u32x4*)(db + r * 128 + (((c0 + 0) ^ (r & 7)) * 16)) = o0;
    *(u32x4*)(db + r * 128 + (((c0 + 1) ^ (r & 7)) * 16)) = o1;
  }
}

// ---------------------------------------------------------------------------
// K2/K5: 128x128x64-tile bf16 GEMM (proven).
// ---------------------------------------------------------------------------
template <int MODE>
__global__ __launch_bounds__(256) void gemm_k(const u16* __restrict__ Aps,
                                              const u16* __restrict__ Bps,
                                              u16* __restrict__ o0,
                                              u16* __restrict__ o1,
                                              u16* __restrict__ o2,
                                              const float* __restrict__ resid,
                                              float* __restrict__ fco) {
  __shared__ __align__(16) u16 As[TILE_ELEMS];
  __shared__ __align__(16) u16 Bs[TILE_ELEMS];
  const int bx = blockIdx.x, by = blockIdx.y;
  const int which = (MODE == 0) ? blockIdx.z : 0;
  const char* Ab = (const char*)(Aps + ((size_t)which * 32 * 16 +
                                        (size_t)bx * 16) * TILE_ELEMS);
  const char* Bb = (const char*)(Bps + ((size_t)which * 128 +
                                        (size_t)by * 16) * TILE_ELEMS);
  const int tid = threadIdx.x, l = tid & 63, g = l >> 4, ln = l & 15;
  const int w = tid >> 6;
  const int wm = (w >> 1) * 64, wn = (w & 1) * 64;
  char* AsB = (char*)As;
  char* BsB = (char*)Bs;
  const f32x4 zero = {0.f, 0.f, 0.f, 0.f};
  f32x4 acc[4][4];
#pragma unroll
  for (int a = 0; a < 4; ++a)
#pragma unroll
    for (int b = 0; b < 4; ++b) acc[a][b] = zero;

  for (int kt = 0; kt < 16; ++kt) {
    const char* at = Ab + kt * TILE_BYTES;
    const char* bt = Bb + kt * TILE_BYTES;
#pragma unroll
    for (int i = 0; i < 4; ++i) {
      gload16(at + i * 4096 + tid * 16, AsB + i * 4096 + w * 1024);
      gload16(bt + i * 4096 + tid * 16, BsB + i * 4096 + w * 1024);
    }
    __syncthreads();
#pragma unroll
    for (int kf = 0; kf < 2; ++kf) {
      bf16x8 av[4], bv[4];
#pragma unroll
      for (int mt = 0; mt < 4; ++mt) {
        const int r = wm + mt * 16 + ln;
        av[mt] = as_bf(*(const u32x4*)(AsB + r * 128 +
                                       (((kf * 4 + g) ^ (r & 7)) * 16)));
      }
#pragma unroll
      for (int nt = 0; nt < 4; ++nt) {
        const int r = wn + nt * 16 + ln;
        bv[nt] = as_bf(*(const u32x4*)(BsB + r * 128 +
                                       (((kf * 4 + g) ^ (r & 7)) * 16)));
      }
#pragma unroll
      for (int mt = 0; mt < 4; ++mt)
#pragma unroll
        for (int nt = 0; nt < 4; ++nt)
          acc[mt][nt] = mfma16(av[mt], bv[nt], acc[mt][nt]);
    }
    __syncthreads();
  }

  const int m0 = bx * 128, n0 = by * 128;
#pragma unroll
  for (int mt = 0; mt < 4; ++mt)
#pragma unroll
    for (int nt = 0; nt < 4; ++nt)
#pragma unroll
      for (int r = 0; r < 4; ++r) {
        const int m = m0 + wm + mt * 16 + 4 * g + r;
        const int n = n0 + wn + nt * 16 + ln;
        const float v = acc[mt][nt][r];
        if (MODE == 0) {
          u16* op = which == 0 ? o0 : which == 1 ? o1 : o2;
          op[(size_t)m * DMODEL + n] = f2bf(v);
        } else {
          fco[(size_t)m * DMODEL + n] = v + resid[(size_t)m * DMODEL + n];
        }
      }
}

// ---------------------------------------------------------------------------
// K3: transpose vh [B*L][H*64] bf16 -> vt8 [B*H][64][L] fp8 e4m3 (proven)
// ---------------------------------------------------------------------------
__global__ __launch_bounds__(256) void vtrans(const u16* __restrict__ vh,
                                              u8* __restrict__ vt8) {
  __shared__ u16 tl[64][72];
  const int l0 = blockIdx.x * 64;
  const int bh = blockIdx.y;
  const int b = bh >> 4, h = bh & 15;
  const int t = threadIdx.x;
  {
    const int i = t >> 2, jc = (t & 3) * 16;
    const u16* src = vh + (size_t)(b * LSEQ + l0 + i) * DMODEL + h * 64 + jc;
    u32x4 u0 = *(const u32x4*)(src);
    u32x4 u1 = *(const u32x4*)(src + 8);
    tl[i][jc + 0] = (u16)u0.x; tl[i][jc + 1] = (u16)(u0.x >> 16);
    tl[i][jc + 2] = (u16)u0.y; tl[i][jc + 3] = (u16)(u0.y >> 16);
    tl[i][jc + 4] = (u16)u0.z; tl[i][jc + 5] = (u16)(u0.z >> 16);
    tl[i][jc + 6] = (u16)u0.w; tl[i][jc + 7] = (u16)(u0.w >> 16);
    tl[i][jc + 8] = (u16)u1.x; tl[i][jc + 9] = (u16)(u1.x >> 16);
    tl[i][jc + 10] = (u16)u1.y; tl[i][jc + 11] = (u16)(u1.y >> 16);
    tl[i][jc + 12] = (u16)u1.z; tl[i][jc + 13] = (u16)(u1.z >> 16);
    tl[i][jc + 14] = (u16)u1.w; tl[i][jc + 15] = (u16)(u1.w >> 16);
  }
  __syncthreads();
  {
    const int j = t >> 2, ic = (t & 3) * 16;
    u32x4 o;
    int p;
    p = __builtin_amdgcn_cvt_pk_fp8_f32(bf2f(tl[ic + 0][j]), bf2f(tl[ic + 1][j]), 0, false);
    p = __builtin_amdgcn_cvt_pk_fp8_f32(bf2f(tl[ic + 2][j]), bf2f(tl[ic + 3][j]), p, true);
    o.x = (u32)p;
    p = __builtin_amdgcn_cvt_pk_fp8_f32(bf2f(tl[ic + 4][j]), bf2f(tl[ic + 5][j]), 0, false);
    p = __builtin_amdgcn_cvt_pk_fp8_f32(bf2f(tl[ic + 6][j]), bf2f(tl[ic + 7][j]), p, true);
    o.y = (u32)p;
    p = __builtin_amdgcn_cvt_pk_fp8_f32(bf2f(tl[ic + 8][j]), bf2f(tl[ic + 9][j]), 0, false);
    p = __builtin_amdgcn_cvt_pk_fp8_f32(bf2f(tl[ic + 10][j]), bf2f(tl[ic + 11][j]), p, true);
    o.z = (u32)p;
    p = __builtin_amdgcn_cvt_pk_fp8_f32(bf2f(tl[ic + 12][j]), bf2f(tl[ic + 13][j]), 0, false);
    p = __builtin_amdgcn_cvt_pk_fp8_f32(bf2f(tl[ic + 14][j]), bf2f(tl[ic + 15][j]), p, true);
    o.w = (u32)p;
    *(u32x4*)(vt8 + ((size_t)bh * 64 + j) * LSEQ + l0 + ic) = o;
  }
}

// ---------------------------------------------------------------------------
// K4: attention — round-15 base (best: 238.1us) with FINE-GRAINED chunk
// interleave of PV and attn stores. Each wave's PV is split into 4 chunks
// (2 kf each) and its 8-row store burst into 4 chunks (16 instrs = 16KB);
// chunks alternate, with parity-opposite order (even: pv,st,...; odd:
// st,pv,...). Store issue spreads over the whole phase-2 window in 16KB
// quanta and each V-load wait drains only earlier chunks (round-15's coarse
// parity still issued 64KB clumps).
// One block = (b,h) x 64 q-rows, 8 waves, P fp8 in 128KB LDS, 1 block/CU.
// ---------------------------------------------------------------------------
__global__ __launch_bounds__(512, 1) void attn_k(const u16* __restrict__ qh,
                                                 const u16* __restrict__ kh,
                                                 const u8* __restrict__ vt8,
                                                 u16* __restrict__ obuf,
                                                 float* __restrict__ attn) {
  __shared__ __align__(16) char smem[64 * 2048 + 64 * 8 * 4 + 64 * 4];
  float* rowsum = (float*)(smem + 64 * 2048);
  float* invl = (float*)(smem + 64 * 2048 + 64 * 8 * 4);
  const int id = blockIdx.x;                   // 1024 blocks
  const int sid = (id & 7) * 128 + (id >> 3);  // 8 XCD x 128
  const int qt = sid & 31, bh = sid >> 5;      // 4 bh-panels per XCD
  const int b = bh >> 4, h = bh & 15;
  const int q0 = qt * 64;
  const int tid = threadIdx.x, w = tid >> 6, l = tid & 63, g = l >> 4,
            ln = l & 15;
  const f32x4 zero = {0.f, 0.f, 0.f, 0.f};

  // Q fragments (rows q0+mt*16+ln, dk = kf*32 + 8g + e)
  bf16x8 aq[4][2];
#pragma unroll
  for (int mt = 0; mt < 4; ++mt)
#pragma unroll
    for (int kf = 0; kf < 2; ++kf)
      aq[mt][kf] = as_bf(*(const u32x4*)(qh +
          (size_t)(b * LSEQ + q0 + mt * 16 + ln) * DMODEL + h * 64 + kf * 32 +
          8 * g));

  // ---- Phase 1: S = Q K^T, exp, P(fp8)->LDS, row-sums (depth-2 K prefetch)
  float rs[16];
#pragma unroll
  for (int i = 0; i < 16; ++i) rs[i] = 0.f;
  const int nb = w * 256;
  const u16* khb = kh + (size_t)b * LSEQ * DMODEL + h * 64;
  u32x4 ka[2], kb2[2];
  ka[0] = *(const u32x4*)(khb + (size_t)(nb + ln) * DMODEL + 8 * g);
  ka[1] = *(const u32x4*)(khb + (size_t)(nb + ln) * DMODEL + 32 + 8 * g);
  kb2[0] = *(const u32x4*)(khb + (size_t)(nb + 16 + ln) * DMODEL + 8 * g);
  kb2[1] = *(const u32x4*)(khb + (size_t)(nb + 16 + ln) * DMODEL + 32 + 8 * g);
#pragma unroll
  for (int nt = 0; nt < 16; ++nt) {
    const int nc = nb + nt * 16;
    const u32x4 c0 = ka[0], c1 = ka[1];
    ka[0] = kb2[0];
    ka[1] = kb2[1];
    if (nt < 14) {
      kb2[0] = *(const u32x4*)(khb + (size_t)(nc + 32 + ln) * DMODEL + 8 * g);
      kb2[1] = *(const u32x4*)(khb + (size_t)(nc + 32 + ln) * DMODEL + 32 + 8 * g);
    }
#pragma unroll
    for (int mt = 0; mt < 4; ++mt) {
      f32x4 s = zero;
      s = mfma16(aq[mt][0], as_bf(c0), s);
      s = mfma16(aq[mt][1], as_bf(c1), s);
#pragma unroll
      for (int r = 0; r < 4; ++r) {
        const float e = __expf(fminf(s[r], 5.5f));
        rs[mt * 4 + r] += e;
        const int m = mt * 16 + 4 * g + r;
        const int pk = __builtin_amdgcn_cvt_pk_fp8_f32(e, e, 0, false);
        *(char*)(smem + m * 2048 + ((nc + ln) ^ ((m & 15) << 3))) = (char)pk;
      }
    }
  }
#pragma unroll
  for (int i = 0; i < 16; ++i) {
    rs[i] += __shfl_xor(rs[i], 1);
    rs[i] += __shfl_xor(rs[i], 2);
    rs[i] += __shfl_xor(rs[i], 4);
    rs[i] += __shfl_xor(rs[i], 8);
  }
  if (ln == 0) {
#pragma unroll
    for (int i = 0; i < 16; ++i) {
      const int m = (i >> 2) * 16 + 4 * g + (i & 3);
      rowsum[m * 8 + w] = rs[i];
    }
  }
  __syncthreads();
  if (tid < 64) {
    float s = 0.f;
#pragma unroll
    for (int j = 0; j < 8; ++j) s += rowsum[tid * 8 + j];
    invl[tid] = 1.0f / s;
  }
  __syncthreads();

  // ---- Phases 2+3: chunk-interleaved PV and stores, parity-opposite order.
  f32x4 oa[4][4];
#pragma unroll
  for (int a = 0; a < 4; ++a)
#pragma unroll
    for (int n = 0; n < 4; ++n) oa[a][n] = zero;
  const u8* vtb = vt8 + (size_t)bh * 64 * LSEQ;
  const int kvb = w * 256;
  u32x2 va[4], vb[4];
#pragma unroll
  for (int nt = 0; nt < 4; ++nt) {
    va[nt] = *(const u32x2*)(vtb + (size_t)(nt * 16 + ln) * LSEQ + kvb + 8 * g);
    vb[nt] =
        *(const u32x2*)(vtb + (size_t)(nt * 16 + ln) * LSEQ + kvb + 32 + 8 * g);
  }

  auto pv_chunk = [&](int c0k) {  // 2 kf iterations: kf = c0k, c0k+1
#pragma unroll
    for (int kfo = 0; kfo < 2; ++kfo) {
      const int kf = c0k + kfo;
      const int kk = kvb + kf * 32 + 8 * g;
      u32x2 cv[4];
#pragma unroll
      for (int nt = 0; nt < 4; ++nt) {
        cv[nt] = va[nt];
        va[nt] = vb[nt];
      }
      if (kf < 6) {
#pragma unroll
        for (int nt = 0; nt < 4; ++nt)
          vb[nt] =
              *(const u32x2*)(vtb + (size_t)(nt * 16 + ln) * LSEQ + kk + 64);
      }
      u32x2 pa[4];
#pragma unroll
      for (int mt = 0; mt < 4; ++mt) {
        const int m = mt * 16 + ln;
        pa[mt] = *(const u32x2*)(smem + m * 2048 + (kk ^ ((m & 15) << 3)));
      }
#pragma unroll
      for (int nt = 0; nt < 4; ++nt)
#pragma unroll
        for (int mt = 0; mt < 4; ++mt)
          oa[mt][nt] = mfma_fp8(pa[mt], cv[nt], oa[mt][nt]);
    }
  };

  auto st_chunk = [&](int ci) {  // ii in [ci*8, ci*8+8), both row-passes
#pragma unroll
    for (int pass = 0; pass < 2; ++pass) {
      const int r2 = w * 8 + pass * 4 + (l >> 4);
      const int c0 = (l & 15) * 4;
      const float inv = invl[r2];
      float* arow = attn + ((size_t)bh * LSEQ + q0 + r2) * LSEQ;
      const int swz = (r2 & 15) << 3;
#pragma unroll
      for (int io = 0; io < 8; ++io) {
        const int col = c0 + (ci * 8 + io) * 64;
        const u32 pw = *(const u32*)(smem + r2 * 2048 + (col ^ swz));
        f32x2 f0 = __builtin_amdgcn_cvt_pk_f32_fp8((int)pw, false);
        f32x2 f1 = __builtin_amdgcn_cvt_pk_f32_fp8((int)pw, true);
        f32x4 o;
        o.x = f0.x * inv;
        o.y = f0.y * inv;
        o.z = f1.x * inv;
        o.w = f1.y * inv;
        __builtin_nontemporal_store(o, (f32x4*)(arow + col));
      }
    }
  };

#pragma unroll
  for (int c = 0; c < 4; ++c) {
    if (w & 1) {
      st_chunk(c);
      pv_chunk(2 * c);
    } else {
      pv_chunk(2 * c);
      st_chunk(c);
    }
  }

  // ---- Epilogue: two-pass cross-wave reduction (64KB partials each pass),
  // lgkm-only barriers so the attn store burst keeps draining.
  float* op = (float*)smem;  // [8 waves][32 rows][64] f32 = 64KB
  bar_lgkm();                // all P reads done
#pragma unroll
  for (int pass = 0; pass < 2; ++pass) {
    if (pass) bar_lgkm();  // pass-0 reduce reads done before overwrite
#pragma unroll
    for (int mt2 = 0; mt2 < 2; ++mt2) {
      const int mt = pass * 2 + mt2;
#pragma unroll
      for (int nt = 0; nt < 4; ++nt)
#pragma unroll
        for (int r = 0; r < 4; ++r) {
          const int mloc = mt2 * 16 + 4 * g + r;
          op[(w * 32 + mloc) * 64 + nt * 16 + ln] = oa[mt][nt][r];
        }
    }
    bar_lgkm();
    if (tid < 256) {
      const int row = tid >> 3, c = tid & 7;
      const int qrow = pass * 32 + row;
      const int m = b * LSEQ + q0 + qrow;
      f32x4 s0 = zero, s1 = zero;
#pragma unroll
      for (int j = 0; j < 8; ++j) {
        const float* pp = op + (j * 32 + row) * 64 + c * 8;
        s0 += *(const f32x4*)pp;
        s1 += *(const f32x4*)(pp + 4);
      }
      const float inv = invl[qrow];
      u32x4 o;
      o.x = pk2(s0.x * inv, s0.y * inv);
      o.y = pk2(s0.z * inv, s0.w * inv);
      o.z = pk2(s1.x * inv, s1.y * inv);
      o.w = pk2(s1.z * inv, s1.w * inv);
      char* db = (char*)obuf + ((size_t)((m >> 7) * 16 + h) * TILE_BYTES);
      const int r = m & 127;
      *(u32x4*)(db + r * 128 + ((c ^ (r & 7)) * 16)) = o;
    }
  }
}

// ---------------------------------------------------------------------------
// K6: LayerNorm over last dim (1024), gamma/beta, f32 in/out
// ---------------------------------------------------------------------------
__global__ __launch_bounds__(256) void lnorm(const float* __restrict__ fco,
                                             const float* __restrict__ gamma,
                                             const float* __restrict__ beta,
                                             float* __restrict__ out) {
  __shared__ float red[2][4];
  const int row = blockIdx.x;
  const int tid = threadIdx.x;
  const f32x4 v = *(const f32x4*)(fco + (size_t)row * DMODEL + tid * 4);
  float s = v.x + v.y + v.z + v.w;
  float q = v.x * v.x + v.y * v.y + v.z * v.z + v.w * v.w;
#pragma unroll
  for (int m = 32; m >= 1; m >>= 1) {
    s += __shfl_xor(s, m);
    q += __shfl_xor(q, m);
  }
  if ((tid & 63) == 0) {
    red[0][tid >> 6] = s;
    red[1][tid >> 6] = q;
  }
  __syncthreads();
  s = red[0][0] + red[0][1] + red[0][2] + red[0][3];
  q = red[1][0] + red[1][1] + red[1][2] + red[1][3];
  const float mean = s * (1.0f / DMODEL);
  const float var = q * (1.0f / DMODEL) - mean * mean;
  const float rst = rsqrtf(var + 1e-6f);
  const f32x4 ga = *(const f32x4*)(gamma + tid * 4);
  const f32x4 be = *(const f32x4*)(beta + tid * 4);
  f32x4 o;
  o.x = (v.x - mean) * rst * ga.x + be.x;
  o.y = (v.y - mean) * rst * ga.y + be.y;
  o.z = (v.z - mean) * rst * ga.z + be.z;
  o.w = (v.w - mean) * rst * ga.w + be.w;
  *(f32x4*)(out + (size_t)row * DMODEL + tid * 4) = o;
}

// ---------------------------------------------------------------------------
extern "C" void kernel_launch(void* const* d_in, const int* in_sizes, int n_in,
                              void* d_out, int out_size, void* d_ws,
                              size_t ws_size, hipStream_t stream) {
  (void)in_sizes; (void)n_in; (void)out_size; (void)ws_size;
  const float* q = (const float*)d_in[0];
  const float* k = (const float*)d_in[1];
  const float* v = (const float*)d_in[2];
  const float* wq = (const float*)d_in[3];
  const float* wk = (const float*)d_in[4];
  const float* wv = (const float*)d_in[5];
  const float* wfc = (const float*)d_in[6];
  const float* gamma = (const float*)d_in[7];
  const float* beta = (const float*)d_in[8];
  float* out = (float*)d_out;
  float* attn = out + (size_t)MROWS * DMODEL;

  char* ws = (char*)d_ws;
  const size_t MB = 1024ull * 1024ull;
  u16* wt_ps = (u16*)(ws);               // 8MB: 4 x [8][16][128][64] bf16
  u16* qkv_ps = (u16*)(ws + 8 * MB);     // 24MB: 3 x [32][16][128][64] bf16
  u16* obuf_ps = (u16*)(ws + 8 * MB);    // 8MB (reuses dead qkv_ps)
  float* fco = (float*)(ws + 16 * MB);   // 16MB (reuses dead qkv_ps)
  u16* qh = (u16*)(ws + 32 * MB);        // [4096][1024] bf16 (already /8)
  u16* kh = (u16*)(ws + 40 * MB);        // [4096][1024] bf16
  u16* vh = (u16*)(ws + 48 * MB);        // [4096][1024] bf16
  u8* vt8 = (u8*)(ws + 56 * MB);         // 4MB: [32][64][2048] fp8 e4m3

  prep<<<dim3(32, 16, 7), 256, 0, stream>>>(q, k, v, wq, wk, wv, wfc, qkv_ps,
                                            wt_ps);
  gemm_k<0><<<dim3(32, 8, 3), 256, 0, stream>>>(qkv_ps, wt_ps, qh, kh, vh,
                                                nullptr, nullptr);
  vtrans<<<dim3(32, 32), 256, 0, stream>>>(vh, vt8);
  attn_k<<<1024, 512, 0, stream>>>(qh, kh, vt8, obuf_ps, attn);
  gemm_k<1><<<dim3(32, 8, 1), 256, 0, stream>>>(
      obuf_ps, wt_ps + 3 * (size_t)(128 * TILE_ELEMS), nullptr, nullptr,
      nullptr, v, fco);
  lnorm<<<4096, 256, 0, stream>>>(fco, gamma, beta, out);
}

// Round 17
// 237.269 us; speedup vs baseline: 1.0155x; 1.0155x over previous
//
#include <hip/hip_runtime.h>
#include <hip/hip_bf16.h>
#include <stdint.h>

#define DEVI __device__ __forceinline__
typedef unsigned short u16;
typedef unsigned int u32;
typedef unsigned char u8;
typedef __attribute__((ext_vector_type(2))) float f32x2;
typedef __attribute__((ext_vector_type(4))) float f32x4;
typedef __attribute__((ext_vector_type(2))) u32 u32x2;
typedef __attribute__((ext_vector_type(4))) u32 u32x4;
typedef __attribute__((ext_vector_type(8))) __bf16 bf16x8;

#define B_ 2
#define LSEQ 2048
#define HN 16
#define DMODEL 1024
#define MROWS (B_ * LSEQ) /* 4096 */
#define TILE_ELEMS (128 * 64)
#define TILE_BYTES (128 * 64 * 2)

DEVI u16 f2bf(float f) {
  u32 u = __float_as_uint(f);
  return (u16)((u + 0x7fffu + ((u >> 16) & 1u)) >> 16);
}
DEVI float bf2f(u16 h) { return __uint_as_float(((u32)h) << 16); }
DEVI u32 pk2(float a, float b) { return (u32)f2bf(a) | ((u32)f2bf(b) << 16); }

DEVI f32x4 mfma16(bf16x8 a, bf16x8 b, f32x4 c) {
  return __builtin_amdgcn_mfma_f32_16x16x32_bf16(a, b, c, 0, 0, 0);
}
DEVI f32x4 mfma_fp8(u32x2 a, u32x2 b, f32x4 c) {
  return __builtin_amdgcn_mfma_f32_16x16x32_fp8_fp8(
      __builtin_bit_cast(long, a), __builtin_bit_cast(long, b), c, 0, 0, 0);
}
DEVI bf16x8 as_bf(u32x4 v) { return __builtin_bit_cast(bf16x8, v); }

// lgkm-only barrier: does NOT drain vmcnt (outstanding global stores keep
// flowing). Rule #18: sched_barrier fences around the asm waitcnt + barrier.
DEVI void bar_lgkm() {
  __builtin_amdgcn_sched_barrier(0);
  asm volatile("s_waitcnt lgkmcnt(0)" ::: "memory");
  __builtin_amdgcn_sched_barrier(0);
  __builtin_amdgcn_s_barrier();
  __builtin_amdgcn_sched_barrier(0);
}

// async global->LDS 16B: LDS dest = wave-uniform base + lane*16
DEVI void gload16(const void* g, void* l) {
  __builtin_amdgcn_global_load_lds(
      (const __attribute__((address_space(1))) void*)g,
      (__attribute__((address_space(3))) void*)l, 16, 0, 0);
}

// ---------------------------------------------------------------------------
// K0: prep — merged activation + weight prep (proven).
// ---------------------------------------------------------------------------
__global__ __launch_bounds__(256) void prep(const float* __restrict__ q,
                                            const float* __restrict__ k,
                                            const float* __restrict__ v,
                                            const float* __restrict__ wq,
                                            const float* __restrict__ wk,
                                            const float* __restrict__ wv,
                                            const float* __restrict__ wfc,
                                            u16* __restrict__ aps,
                                            u16* __restrict__ wt) {
  const int z = blockIdx.z;
  const int t = threadIdx.x;
  if (z < 3) {
    const float* src = z == 0 ? q : z == 1 ? k : v;
    const int mt = blockIdx.x, kt = blockIdx.y;
    char* db = (char*)(aps + ((size_t)z * 32 * 16 + (size_t)mt * 16 + kt) *
                                 TILE_ELEMS);
#pragma unroll
    for (int i = 0; i < 4; ++i) {
      const int ch = t + i * 256;
      const int r = ch >> 3, c = ch & 7;
      const float* sp = src + (size_t)(mt * 128 + r) * DMODEL + kt * 64 + c * 8;
      f32x4 a = *(const f32x4*)sp;
      f32x4 b = *(const f32x4*)(sp + 4);
      u32x4 o;
      o.x = pk2(a.x, a.y);
      o.y = pk2(a.z, a.w);
      o.z = pk2(b.x, b.y);
      o.w = pk2(b.z, b.w);
      *(u32x4*)(db + r * 128 + ((c ^ (r & 7)) * 16)) = o;
    }
    return;
  }
  if (blockIdx.x >= 16) return;
  __shared__ float tl[64][65];
  const int which = z - 3;
  const float* src = which == 0 ? wq : which == 1 ? wk : which == 2 ? wv : wfc;
  const float scale = which == 0 ? 0.125f : 1.0f;
  const int kt = blockIdx.x;
  const int k0 = kt * 64, n0 = blockIdx.y * 64;
  {
    const int i = t >> 2, jc = (t & 3) * 16;
#pragma unroll
    for (int x = 0; x < 4; ++x) {
      f32x4 f = *(const f32x4*)(src + (size_t)(k0 + i) * DMODEL + n0 + jc + 4 * x);
      tl[i][jc + 4 * x + 0] = f.x;
      tl[i][jc + 4 * x + 1] = f.y;
      tl[i][jc + 4 * x + 2] = f.z;
      tl[i][jc + 4 * x + 3] = f.w;
    }
  }
  __syncthreads();
  {
    const int j = t >> 2, ic = (t & 3) * 16;
    u32x4 o0, o1;
    o0.x = pk2(tl[ic + 0][j] * scale, tl[ic + 1][j] * scale);
    o0.y = pk2(tl[ic + 2][j] * scale, tl[ic + 3][j] * scale);
    o0.z = pk2(tl[ic + 4][j] * scale, tl[ic + 5][j] * scale);
    o0.w = pk2(tl[ic + 6][j] * scale, tl[ic + 7][j] * scale);
    o1.x = pk2(tl[ic + 8][j] * scale, tl[ic + 9][j] * scale);
    o1.y = pk2(tl[ic + 10][j] * scale, tl[ic + 11][j] * scale);
    o1.z = pk2(tl[ic + 12][j] * scale, tl[ic + 13][j] * scale);
    o1.w = pk2(tl[ic + 14][j] * scale, tl[ic + 15][j] * scale);
    const int ntile = blockIdx.y >> 1;
    const int r = ((blockIdx.y & 1) << 6) + j;
    const int c0 = (t & 3) * 2;
    char* db = (char*)(wt + ((size_t)which * 128 + (size_t)ntile * 16 + kt) *
                                TILE_ELEMS);
    *(u32x4*)(db + r * 128 + (((c0 + 0) ^ (r & 7)) * 16)) = o0;
    *(u32x4*)(db + r * 128 + (((c0 + 1) ^ (r & 7)) * 16)) = o1;
  }
}

// ---------------------------------------------------------------------------
// K2/K5: 128x128x64-tile bf16 GEMM (proven).
// ---------------------------------------------------------------------------
template <int MODE>
__global__ __launch_bounds__(256) void gemm_k(const u16* __restrict__ Aps,
                                              const u16* __restrict__ Bps,
                                              u16* __restrict__ o0,
                                              u16* __restrict__ o1,
                                              u16* __restrict__ o2,
                                              const float* __restrict__ resid,
                                              float* __restrict__ fco) {
  __shared__ __align__(16) u16 As[TILE_ELEMS];
  __shared__ __align__(16) u16 Bs[TILE_ELEMS];
  const int bx = blockIdx.x, by = blockIdx.y;
  const int which = (MODE == 0) ? blockIdx.z : 0;
  const char* Ab = (const char*)(Aps + ((size_t)which * 32 * 16 +
                                        (size_t)bx * 16) * TILE_ELEMS);
  const char* Bb = (const char*)(Bps + ((size_t)which * 128 +
                                        (size_t)by * 16) * TILE_ELEMS);
  const int tid = threadIdx.x, l = tid & 63, g = l >> 4, ln = l & 15;
  const int w = tid >> 6;
  const int wm = (w >> 1) * 64, wn = (w & 1) * 64;
  char* AsB = (char*)As;
  char* BsB = (char*)Bs;
  const f32x4 zero = {0.f, 0.f, 0.f, 0.f};
  f32x4 acc[4][4];
#pragma unroll
  for (int a = 0; a < 4; ++a)
#pragma unroll
    for (int b = 0; b < 4; ++b) acc[a][b] = zero;

  for (int kt = 0; kt < 16; ++kt) {
    const char* at = Ab + kt * TILE_BYTES;
    const char* bt = Bb + kt * TILE_BYTES;
#pragma unroll
    for (int i = 0; i < 4; ++i) {
      gload16(at + i * 4096 + tid * 16, AsB + i * 4096 + w * 1024);
      gload16(bt + i * 4096 + tid * 16, BsB + i * 4096 + w * 1024);
    }
    __syncthreads();
#pragma unroll
    for (int kf = 0; kf < 2; ++kf) {
      bf16x8 av[4], bv[4];
#pragma unroll
      for (int mt = 0; mt < 4; ++mt) {
        const int r = wm + mt * 16 + ln;
        av[mt] = as_bf(*(const u32x4*)(AsB + r * 128 +
                                       (((kf * 4 + g) ^ (r & 7)) * 16)));
      }
#pragma unroll
      for (int nt = 0; nt < 4; ++nt) {
        const int r = wn + nt * 16 + ln;
        bv[nt] = as_bf(*(const u32x4*)(BsB + r * 128 +
                                       (((kf * 4 + g) ^ (r & 7)) * 16)));
      }
#pragma unroll
      for (int mt = 0; mt < 4; ++mt)
#pragma unroll
        for (int nt = 0; nt < 4; ++nt)
          acc[mt][nt] = mfma16(av[mt], bv[nt], acc[mt][nt]);
    }
    __syncthreads();
  }

  const int m0 = bx * 128, n0 = by * 128;
#pragma unroll
  for (int mt = 0; mt < 4; ++mt)
#pragma unroll
    for (int nt = 0; nt < 4; ++nt)
#pragma unroll
      for (int r = 0; r < 4; ++r) {
        const int m = m0 + wm + mt * 16 + 4 * g + r;
        const int n = n0 + wn + nt * 16 + ln;
        const float v = acc[mt][nt][r];
        if (MODE == 0) {
          u16* op = which == 0 ? o0 : which == 1 ? o1 : o2;
          op[(size_t)m * DMODEL + n] = f2bf(v);
        } else {
          fco[(size_t)m * DMODEL + n] = v + resid[(size_t)m * DMODEL + n];
        }
      }
}

// ---------------------------------------------------------------------------
// K3: transpose vh [B*L][H*64] bf16 -> vt8 [B*H][64][L] fp8 e4m3 (proven)
// ---------------------------------------------------------------------------
__global__ __launch_bounds__(256) void vtrans(const u16* __restrict__ vh,
                                              u8* __restrict__ vt8) {
  __shared__ u16 tl[64][72];
  const int l0 = blockIdx.x * 64;
  const int bh = blockIdx.y;
  const int b = bh >> 4, h = bh & 15;
  const int t = threadIdx.x;
  {
    const int i = t >> 2, jc = (t & 3) * 16;
    const u16* src = vh + (size_t)(b * LSEQ + l0 + i) * DMODEL + h * 64 + jc;
    u32x4 u0 = *(const u32x4*)(src);
    u32x4 u1 = *(const u32x4*)(src + 8);
    tl[i][jc + 0] = (u16)u0.x; tl[i][jc + 1] = (u16)(u0.x >> 16);
    tl[i][jc + 2] = (u16)u0.y; tl[i][jc + 3] = (u16)(u0.y >> 16);
    tl[i][jc + 4] = (u16)u0.z; tl[i][jc + 5] = (u16)(u0.z >> 16);
    tl[i][jc + 6] = (u16)u0.w; tl[i][jc + 7] = (u16)(u0.w >> 16);
    tl[i][jc + 8] = (u16)u1.x; tl[i][jc + 9] = (u16)(u1.x >> 16);
    tl[i][jc + 10] = (u16)u1.y; tl[i][jc + 11] = (u16)(u1.y >> 16);
    tl[i][jc + 12] = (u16)u1.z; tl[i][jc + 13] = (u16)(u1.z >> 16);
    tl[i][jc + 14] = (u16)u1.w; tl[i][jc + 15] = (u16)(u1.w >> 16);
  }
  __syncthreads();
  {
    const int j = t >> 2, ic = (t & 3) * 16;
    u32x4 o;
    int p;
    p = __builtin_amdgcn_cvt_pk_fp8_f32(bf2f(tl[ic + 0][j]), bf2f(tl[ic + 1][j]), 0, false);
    p = __builtin_amdgcn_cvt_pk_fp8_f32(bf2f(tl[ic + 2][j]), bf2f(tl[ic + 3][j]), p, true);
    o.x = (u32)p;
    p = __builtin_amdgcn_cvt_pk_fp8_f32(bf2f(tl[ic + 4][j]), bf2f(tl[ic + 5][j]), 0, false);
    p = __builtin_amdgcn_cvt_pk_fp8_f32(bf2f(tl[ic + 6][j]), bf2f(tl[ic + 7][j]), p, true);
    o.y = (u32)p;
    p = __builtin_amdgcn_cvt_pk_fp8_f32(bf2f(tl[ic + 8][j]), bf2f(tl[ic + 9][j]), 0, false);
    p = __builtin_amdgcn_cvt_pk_fp8_f32(bf2f(tl[ic + 10][j]), bf2f(tl[ic + 11][j]), p, true);
    o.z = (u32)p;
    p = __builtin_amdgcn_cvt_pk_fp8_f32(bf2f(tl[ic + 12][j]), bf2f(tl[ic + 13][j]), 0, false);
    p = __builtin_amdgcn_cvt_pk_fp8_f32(bf2f(tl[ic + 14][j]), bf2f(tl[ic + 15][j]), p, true);
    o.w = (u32)p;
    *(u32x4*)(vt8 + ((size_t)bh * 64 + j) * LSEQ + l0 + ic) = o;
  }
}

// ---------------------------------------------------------------------------
// K4: attention — round-15 configuration (measured best: 238.1us).
// One block = (b,h) x 64 q-rows, 8 waves, P fp8 in 128KB LDS, 1 block/CU.
// WAVE-PARITY PHASE STAGGER: each wave stores only its own 8 attn rows; ODD
// waves run stores->PV, EVEN waves run PV->stores, so ~half the waves feed
// the store pipe while the other half compute (per-wave vmcnt is
// independent). Depth-2 K/V register prefetch; lgkm-only barriers after
// stores; bijective XCD swizzle.
// ---------------------------------------------------------------------------
__global__ __launch_bounds__(512, 1) void attn_k(const u16* __restrict__ qh,
                                                 const u16* __restrict__ kh,
                                                 const u8* __restrict__ vt8,
                                                 u16* __restrict__ obuf,
                                                 float* __restrict__ attn) {
  __shared__ __align__(16) char smem[64 * 2048 + 64 * 8 * 4 + 64 * 4];
  float* rowsum = (float*)(smem + 64 * 2048);
  float* invl = (float*)(smem + 64 * 2048 + 64 * 8 * 4);
  const int id = blockIdx.x;                   // 1024 blocks
  const int sid = (id & 7) * 128 + (id >> 3);  // 8 XCD x 128
  const int qt = sid & 31, bh = sid >> 5;      // 4 bh-panels per XCD
  const int b = bh >> 4, h = bh & 15;
  const int q0 = qt * 64;
  const int tid = threadIdx.x, w = tid >> 6, l = tid & 63, g = l >> 4,
            ln = l & 15;
  const f32x4 zero = {0.f, 0.f, 0.f, 0.f};

  // Q fragments (rows q0+mt*16+ln, dk = kf*32 + 8g + e)
  bf16x8 aq[4][2];
#pragma unroll
  for (int mt = 0; mt < 4; ++mt)
#pragma unroll
    for (int kf = 0; kf < 2; ++kf)
      aq[mt][kf] = as_bf(*(const u32x4*)(qh +
          (size_t)(b * LSEQ + q0 + mt * 16 + ln) * DMODEL + h * 64 + kf * 32 +
          8 * g));

  // ---- Phase 1: S = Q K^T, exp, P(fp8)->LDS, row-sums (depth-2 K prefetch)
  float rs[16];
#pragma unroll
  for (int i = 0; i < 16; ++i) rs[i] = 0.f;
  const int nb = w * 256;
  const u16* khb = kh + (size_t)b * LSEQ * DMODEL + h * 64;
  u32x4 ka[2], kb2[2];
  ka[0] = *(const u32x4*)(khb + (size_t)(nb + ln) * DMODEL + 8 * g);
  ka[1] = *(const u32x4*)(khb + (size_t)(nb + ln) * DMODEL + 32 + 8 * g);
  kb2[0] = *(const u32x4*)(khb + (size_t)(nb + 16 + ln) * DMODEL + 8 * g);
  kb2[1] = *(const u32x4*)(khb + (size_t)(nb + 16 + ln) * DMODEL + 32 + 8 * g);
#pragma unroll
  for (int nt = 0; nt < 16; ++nt) {
    const int nc = nb + nt * 16;
    const u32x4 c0 = ka[0], c1 = ka[1];
    ka[0] = kb2[0];
    ka[1] = kb2[1];
    if (nt < 14) {
      kb2[0] = *(const u32x4*)(khb + (size_t)(nc + 32 + ln) * DMODEL + 8 * g);
      kb2[1] = *(const u32x4*)(khb + (size_t)(nc + 32 + ln) * DMODEL + 32 + 8 * g);
    }
#pragma unroll
    for (int mt = 0; mt < 4; ++mt) {
      f32x4 s = zero;
      s = mfma16(aq[mt][0], as_bf(c0), s);
      s = mfma16(aq[mt][1], as_bf(c1), s);
#pragma unroll
      for (int r = 0; r < 4; ++r) {
        const float e = __expf(fminf(s[r], 5.5f));
        rs[mt * 4 + r] += e;
        const int m = mt * 16 + 4 * g + r;
        const int pk = __builtin_amdgcn_cvt_pk_fp8_f32(e, e, 0, false);
        *(char*)(smem + m * 2048 + ((nc + ln) ^ ((m & 15) << 3))) = (char)pk;
      }
    }
  }
#pragma unroll
  for (int i = 0; i < 16; ++i) {
    rs[i] += __shfl_xor(rs[i], 1);
    rs[i] += __shfl_xor(rs[i], 2);
    rs[i] += __shfl_xor(rs[i], 4);
    rs[i] += __shfl_xor(rs[i], 8);
  }
  if (ln == 0) {
#pragma unroll
    for (int i = 0; i < 16; ++i) {
      const int m = (i >> 2) * 16 + 4 * g + (i & 3);
      rowsum[m * 8 + w] = rs[i];
    }
  }
  __syncthreads();
  if (tid < 64) {
    float s = 0.f;
#pragma unroll
    for (int j = 0; j < 8; ++j) s += rowsum[tid * 8 + j];
    invl[tid] = 1.0f / s;
  }
  __syncthreads();

  // ---- Phases 2+3 in wave-parity order.
  f32x4 oa[4][4];
#pragma unroll
  for (int a = 0; a < 4; ++a)
#pragma unroll
    for (int n = 0; n < 4; ++n) oa[a][n] = zero;

  auto do_pv = [&]() {
    // O = P V (fp8 x fp8), wave w covers k-cols [w*256, w*256+256), depth-2
    const u8* vtb = vt8 + (size_t)bh * 64 * LSEQ;
    const int kvb = w * 256;
    u32x2 va[4], vb[4];
#pragma unroll
    for (int nt = 0; nt < 4; ++nt) {
      va[nt] =
          *(const u32x2*)(vtb + (size_t)(nt * 16 + ln) * LSEQ + kvb + 8 * g);
      vb[nt] = *(const u32x2*)(vtb + (size_t)(nt * 16 + ln) * LSEQ + kvb + 32 +
                               8 * g);
    }
#pragma unroll
    for (int kf = 0; kf < 8; ++kf) {
      const int kk = kvb + kf * 32 + 8 * g;
      u32x2 cv[4];
#pragma unroll
      for (int nt = 0; nt < 4; ++nt) {
        cv[nt] = va[nt];
        va[nt] = vb[nt];
      }
      if (kf < 6) {
#pragma unroll
        for (int nt = 0; nt < 4; ++nt)
          vb[nt] =
              *(const u32x2*)(vtb + (size_t)(nt * 16 + ln) * LSEQ + kk + 64);
      }
      u32x2 pa[4];
#pragma unroll
      for (int mt = 0; mt < 4; ++mt) {
        const int m = mt * 16 + ln;
        pa[mt] = *(const u32x2*)(smem + m * 2048 + (kk ^ ((m & 15) << 3)));
      }
#pragma unroll
      for (int nt = 0; nt < 4; ++nt)
#pragma unroll
        for (int mt = 0; mt < 4; ++mt)
          oa[mt][nt] = mfma_fp8(pa[mt], cv[nt], oa[mt][nt]);
    }
  };

  auto do_store = [&]() {
    // wave w stores its 8 rows [w*8, w*8+8): 2 passes x 4 rows, per instr
    // 16 lanes x 16B = 256B contiguous per row (proven coalesced shape).
#pragma unroll
    for (int pass = 0; pass < 2; ++pass) {
      const int r2 = w * 8 + pass * 4 + (l >> 4);
      const int c0 = (l & 15) * 4;
      const float inv = invl[r2];
      float* arow = attn + ((size_t)bh * LSEQ + q0 + r2) * LSEQ;
      const int swz = (r2 & 15) << 3;
#pragma unroll 4
      for (int ii = 0; ii < 32; ++ii) {
        const int col = c0 + ii * 64;
        const u32 pw = *(const u32*)(smem + r2 * 2048 + (col ^ swz));
        f32x2 f0 = __builtin_amdgcn_cvt_pk_f32_fp8((int)pw, false);
        f32x2 f1 = __builtin_amdgcn_cvt_pk_f32_fp8((int)pw, true);
        f32x4 o;
        o.x = f0.x * inv;
        o.y = f0.y * inv;
        o.z = f1.x * inv;
        o.w = f1.y * inv;
        __builtin_nontemporal_store(o, (f32x4*)(arow + col));
      }
    }
  };

  if (w & 1) {
    do_store();
    do_pv();
  } else {
    do_pv();
    do_store();
  }

  // ---- Epilogue: two-pass cross-wave reduction (64KB partials each pass),
  // lgkm-only barriers so the attn store burst keeps draining.
  float* op = (float*)smem;  // [8 waves][32 rows][64] f32 = 64KB
  bar_lgkm();                // all P reads done
#pragma unroll
  for (int pass = 0; pass < 2; ++pass) {
    if (pass) bar_lgkm();  // pass-0 reduce reads done before overwrite
#pragma unroll
    for (int mt2 = 0; mt2 < 2; ++mt2) {
      const int mt = pass * 2 + mt2;
#pragma unroll
      for (int nt = 0; nt < 4; ++nt)
#pragma unroll
        for (int r = 0; r < 4; ++r) {
          const int mloc = mt2 * 16 + 4 * g + r;
          op[(w * 32 + mloc) * 64 + nt * 16 + ln] = oa[mt][nt][r];
        }
    }
    bar_lgkm();
    if (tid < 256) {
      const int row = tid >> 3, c = tid & 7;
      const int qrow = pass * 32 + row;
      const int m = b * LSEQ + q0 + qrow;
      f32x4 s0 = zero, s1 = zero;
#pragma unroll
      for (int j = 0; j < 8; ++j) {
        const float* pp = op + (j * 32 + row) * 64 + c * 8;
        s0 += *(const f32x4*)pp;
        s1 += *(const f32x4*)(pp + 4);
      }
      const float inv = invl[qrow];
      u32x4 o;
      o.x = pk2(s0.x * inv, s0.y * inv);
      o.y = pk2(s0.z * inv, s0.w * inv);
      o.z = pk2(s1.x * inv, s1.y * inv);
      o.w = pk2(s1.z * inv, s1.w * inv);
      char* db = (char*)obuf + ((size_t)((m >> 7) * 16 + h) * TILE_BYTES);
      const int r = m & 127;
      *(u32x4*)(db + r * 128 + ((c ^ (r & 7)) * 16)) = o;
    }
  }
}

// ---------------------------------------------------------------------------
// K6: LayerNorm over last dim (1024), gamma/beta, f32 in/out
// ---------------------------------------------------------------------------
__global__ __launch_bounds__(256) void lnorm(const float* __restrict__ fco,
                                             const float* __restrict__ gamma,
                                             const float* __restrict__ beta,
                                             float* __restrict__ out) {
  __shared__ float red[2][4];
  const int row = blockIdx.x;
  const int tid = threadIdx.x;
  const f32x4 v = *(const f32x4*)(fco + (size_t)row * DMODEL + tid * 4);
  float s = v.x + v.y + v.z + v.w;
  float q = v.x * v.x + v.y * v.y + v.z * v.z + v.w * v.w;
#pragma unroll
  for (int m = 32; m >= 1; m >>= 1) {
    s += __shfl_xor(s, m);
    q += __shfl_xor(q, m);
  }
  if ((tid & 63) == 0) {
    red[0][tid >> 6] = s;
    red[1][tid >> 6] = q;
  }
  __syncthreads();
  s = red[0][0] + red[0][1] + red[0][2] + red[0][3];
  q = red[1][0] + red[1][1] + red[1][2] + red[1][3];
  const float mean = s * (1.0f / DMODEL);
  const float var = q * (1.0f / DMODEL) - mean * mean;
  const float rst = rsqrtf(var + 1e-6f);
  const f32x4 ga = *(const f32x4*)(gamma + tid * 4);
  const f32x4 be = *(const f32x4*)(beta + tid * 4);
  f32x4 o;
  o.x = (v.x - mean) * rst * ga.x + be.x;
  o.y = (v.y - mean) * rst * ga.y + be.y;
  o.z = (v.z - mean) * rst * ga.z + be.z;
  o.w = (v.w - mean) * rst * ga.w + be.w;
  *(f32x4*)(out + (size_t)row * DMODEL + tid * 4) = o;
}

// ---------------------------------------------------------------------------
extern "C" void kernel_launch(void* const* d_in, const int* in_sizes, int n_in,
                              void* d_out, int out_size, void* d_ws,
                              size_t ws_size, hipStream_t stream) {
  (void)in_sizes; (void)n_in; (void)out_size; (void)ws_size;
  const float* q = (const float*)d_in[0];
  const float* k = (const float*)d_in[1];
  const float* v = (const float*)d_in[2];
  const float* wq = (const float*)d_in[3];
  const float* wk = (const float*)d_in[4];
  const float* wv = (const float*)d_in[5];
  const float* wfc = (const float*)d_in[6];
  const float* gamma = (const float*)d_in[7];
  const float* beta = (const float*)d_in[8];
  float* out = (float*)d_out;
  float* attn = out + (size_t)MROWS * DMODEL;

  char* ws = (char*)d_ws;
  const size_t MB = 1024ull * 1024ull;
  u16* wt_ps = (u16*)(ws);               // 8MB: 4 x [8][16][128][64] bf16
  u16* qkv_ps = (u16*)(ws + 8 * MB);     // 24MB: 3 x [32][16][128][64] bf16
  u16* obuf_ps = (u16*)(ws + 8 * MB);    // 8MB (reuses dead qkv_ps)
  float* fco = (float*)(ws + 16 * MB);   // 16MB (reuses dead qkv_ps)
  u16* qh = (u16*)(ws + 32 * MB);        // [4096][1024] bf16 (already /8)
  u16* kh = (u16*)(ws + 40 * MB);        // [4096][1024] bf16
  u16* vh = (u16*)(ws + 48 * MB);        // [4096][1024] bf16
  u8* vt8 = (u8*)(ws + 56 * MB);         // 4MB: [32][64][2048] fp8 e4m3

  prep<<<dim3(32, 16, 7), 256, 0, stream>>>(q, k, v, wq, wk, wv, wfc, qkv_ps,
                                            wt_ps);
  gemm_k<0><<<dim3(32, 8, 3), 256, 0, stream>>>(qkv_ps, wt_ps, qh, kh, vh,
                                                nullptr, nullptr);
  vtrans<<<dim3(32, 32), 256, 0, stream>>>(vh, vt8);
  attn_k<<<1024, 512, 0, stream>>>(qh, kh, vt8, obuf_ps, attn);
  gemm_k<1><<<dim3(32, 8, 1), 256, 0, stream>>>(
      obuf_ps, wt_ps + 3 * (size_t)(128 * TILE_ELEMS), nullptr, nullptr,
      nullptr, v, fco);
  lnorm<<<4096, 256, 0, stream>>>(fco, gamma, beta, out);
}